// Round 17
// baseline (6355.083 us; speedup 1.0000x reference)
//
#include <hip/hip_runtime.h>

typedef unsigned short ushort_t;
typedef unsigned int uint32;

typedef float f32x4 __attribute__((ext_vector_type(4)));
typedef __bf16 bf16x8 __attribute__((ext_vector_type(8)));
typedef unsigned short us8 __attribute__((ext_vector_type(8)));
typedef unsigned short us4 __attribute__((ext_vector_type(4)));

#define TSEQ 2048
#define DMODEL 4096

__device__ __forceinline__ ushort_t f2bf(float f) {
  uint32 u = __builtin_bit_cast(uint32, f);
  u += 0x7FFFu + ((u >> 16) & 1u);   // RNE (no NaNs in this problem)
  return (ushort_t)(u >> 16);
}
__device__ __forceinline__ float bf2f(ushort_t u) {
  return __builtin_bit_cast(float, ((uint32)u) << 16);
}

__device__ __forceinline__ void gload_lds16(const void* g, void* l) {
  auto gp = (const __attribute__((address_space(1))) void*)g;
  auto lp = (__attribute__((address_space(3))) void*)l;
  __builtin_amdgcn_global_load_lds(gp, lp, 16, 0, 0);
}

// ---- prep: z=0..3 transpose+cast W_z (K x N fp32 -> N x K bf16); z=4 cast x ----
__global__ __launch_bounds__(256) void k_prep(const float* __restrict__ W0,
                                              const float* __restrict__ W1,
                                              const float* __restrict__ W2,
                                              const float* __restrict__ W3,
                                              const float* __restrict__ x,
                                              ushort_t* __restrict__ WTbase,
                                              ushort_t* __restrict__ xb) {
  const int tid = threadIdx.x;
  const int n0 = blockIdx.x * 64, k0 = blockIdx.y * 64;
  if (blockIdx.z == 4) {
    #pragma unroll
    for (int it = 0; it < 4; ++it) {
      int e = it * 256 + tid;
      int r = e >> 4, c4 = e & 15;
      float4 v = *(const float4*)(x + (size_t)(k0 + r) * DMODEL + n0 + c4 * 4);
      us4 o; o[0] = f2bf(v.x); o[1] = f2bf(v.y); o[2] = f2bf(v.z); o[3] = f2bf(v.w);
      *(us4*)(xb + (size_t)(k0 + r) * DMODEL + n0 + c4 * 4) = o;
    }
    return;
  }
  __shared__ __align__(16) ushort_t ts[64 * 72];
  const float* Ws[4] = {W0, W1, W2, W3};
  const float* W = Ws[blockIdx.z];
  ushort_t* WT = WTbase + (size_t)blockIdx.z * DMODEL * DMODEL;
  #pragma unroll
  for (int it = 0; it < 4; ++it) {
    int e = it * 256 + tid;
    int r = e >> 4, c4 = e & 15;
    float4 v = *(const float4*)(W + (size_t)(k0 + r) * DMODEL + n0 + c4 * 4);
    us4 o; o[0] = f2bf(v.x); o[1] = f2bf(v.y); o[2] = f2bf(v.z); o[3] = f2bf(v.w);
    *(us4*)&ts[r * 72 + c4 * 4] = o;
  }
  __syncthreads();
  #pragma unroll
  for (int it = 0; it < 4; ++it) {
    int e = it * 256 + tid;
    int r2 = e >> 4, c4 = e & 15;
    us4 o;
    #pragma unroll
    for (int j = 0; j < 4; ++j) o[j] = ts[(c4 * 4 + j) * 72 + r2];
    *(us4*)(WT + (size_t)(n0 + r2) * DMODEL + k0 + c4 * 4) = o;
  }
}

// ---------------- 128x256 GEMM core; SBUF=true: single-buffer 24KB (4 blocks/CU),
// SBUF=false: double-buffer 48KB (2 blocks/CU, R15 measured-best) ----------------
template <bool OUT_BF16, bool SBUF>
__device__ __forceinline__
void gemm_core(const ushort_t* __restrict__ A, const ushort_t* __restrict__ Bt,
               void* __restrict__ Cv, int M, int N, int K, bool rope,
               const float* __restrict__ fc, const float* __restrict__ fs,
               int wgx, int nwgx) {
  __shared__ __align__(16) ushort_t As[SBUF ? 1 : 2][128 * 32];
  __shared__ __align__(16) ushort_t Bs[SBUF ? 1 : 2][256 * 32];
  const int tid = threadIdx.x;
  const int w = tid >> 6, l = tid & 63;
  const int wr = w >> 2, wc = w & 3;
  const int lg = l >> 4, lc = l & 15;

  // XCD-bijective swizzle over the x-extent (nwgx % 8 == 0)
  const int cpx = nwgx >> 3;
  const int wg = (wgx & 7) * cpx + (wgx >> 3);
  const int nbn = N >> 8;
  const int bm = wg / nbn, bn = wg % nbn;

  const ushort_t* Ab = A + (size_t)(bm * 128) * K;
  const ushort_t* Bb = Bt + (size_t)(bn * 256) * K;

  const int slotA = tid;
  const int rowA = slotA >> 2;
  const int chA = (slotA & 3) ^ (rowA & 3) ^ (2 * ((rowA >> 2) & 1));
  const ushort_t* gAp = Ab + (size_t)rowA * K + chA * 8;
  const int dstA = (w * 64) * 8;

  const int rowB0 = tid >> 2, rowB1 = (512 + tid) >> 2;
  const int chB0 = (tid & 3) ^ (rowB0 & 3) ^ (2 * ((rowB0 >> 2) & 1));
  const int chB1 = (tid & 3) ^ (rowB1 & 3) ^ (2 * ((rowB1 >> 2) & 1));
  const ushort_t* gBp0 = Bb + (size_t)rowB0 * K + chB0 * 8;
  const ushort_t* gBp1 = Bb + (size_t)rowB1 * K + chB1 * 8;
  const int dstB0 = (w * 64) * 8;
  const int dstB1 = (512 + w * 64) * 8;

  const int rswz = (lg ^ (lc & 3) ^ (2 * ((lc >> 2) & 1))) * 8;
  int offA[4], offB[4];
  #pragma unroll
  for (int m = 0; m < 4; ++m) offA[m] = (wr * 64 + m * 16 + lc) * 32 + rswz;
  #pragma unroll
  for (int n = 0; n < 4; ++n) offB[n] = (wc * 64 + n * 16 + lc) * 32 + rswz;

  f32x4 acc[4][4];
  #pragma unroll
  for (int m = 0; m < 4; ++m)
    #pragma unroll
    for (int n = 0; n < 4; ++n) acc[m][n] = (f32x4){0.f, 0.f, 0.f, 0.f};

  const int NT = K >> 5;
  auto stage = [&](int t, int buf) {
    const int k0 = t << 5;
    gload_lds16(gAp + k0, &As[buf][dstA]);
    gload_lds16(gBp0 + k0, &Bs[buf][dstB0]);
    gload_lds16(gBp1 + k0, &Bs[buf][dstB1]);
  };

  if (SBUF) {
    // m97 2-barrier pattern: bar -> stage -> vmcnt(0) -> bar -> compute.
    // 4 co-resident blocks' MFMA covers the drain (TLP).
    for (int t = 0; t < NT; ++t) {
      if (t > 0) {
        asm volatile("" ::: "memory");
        __builtin_amdgcn_s_barrier();   // reads of tile t-1 complete
      }
      stage(t, 0);
      asm volatile("s_waitcnt vmcnt(0)" ::: "memory");
      __builtin_amdgcn_s_barrier();

      bf16x8 af[4], bfv[4];
      #pragma unroll
      for (int m = 0; m < 4; ++m) af[m] = *(const bf16x8*)&As[0][offA[m]];
      #pragma unroll
      for (int n = 0; n < 4; ++n) bfv[n] = *(const bf16x8*)&Bs[0][offB[n]];
      __builtin_amdgcn_s_setprio(1);
      #pragma unroll
      for (int m = 0; m < 4; ++m)
        #pragma unroll
        for (int n = 0; n < 4; ++n)
          acc[m][n] = __builtin_amdgcn_mfma_f32_16x16x32_bf16(af[m], bfv[n], acc[m][n], 0, 0, 0);
      __builtin_amdgcn_s_setprio(0);
    }
  } else {
    stage(0, 0);
    asm volatile("s_waitcnt vmcnt(0)" ::: "memory");
    __builtin_amdgcn_s_barrier();

    for (int t = 0; t < NT; ++t) {
      const int cur = t & 1;
      if (t + 1 < NT) stage(t + 1, cur ^ 1);

      bf16x8 af[4], bfv[4];
      #pragma unroll
      for (int m = 0; m < 4; ++m) af[m] = *(const bf16x8*)&As[cur][offA[m]];
      #pragma unroll
      for (int n = 0; n < 4; ++n) bfv[n] = *(const bf16x8*)&Bs[cur][offB[n]];
      __builtin_amdgcn_s_setprio(1);
      #pragma unroll
      for (int m = 0; m < 4; ++m)
        #pragma unroll
        for (int n = 0; n < 4; ++n)
          acc[m][n] = __builtin_amdgcn_mfma_f32_16x16x32_bf16(af[m], bfv[n], acc[m][n], 0, 0, 0);
      __builtin_amdgcn_s_setprio(0);

      if (t + 1 < NT) {
        asm volatile("s_waitcnt vmcnt(0)" ::: "memory");
        __builtin_amdgcn_s_barrier();
      }
    }
  }

  #pragma unroll
  for (int m = 0; m < 4; ++m) {
    int row0 = bm * 128 + wr * 64 + m * 16 + lg * 4;
    #pragma unroll
    for (int n = 0; n < 4; ++n) {
      int col = bn * 256 + wc * 64 + n * 16 + lc;
      if (rope) {
        int i0 = (col & 127) >> 1;
        #pragma unroll
        for (int r = 0; r < 4; ++r) {
          int tt = (row0 + r) & (TSEQ - 1);
          float c = fc[tt * 64 + i0];
          float s = fs[tt * 64 + i0];
          float v = acc[m][n][r];
          float p = __shfl_xor(v, 1);
          float ov = (lc & 1) ? (p * s + v * c) : (v * c - p * s);
          ((ushort_t*)Cv)[(size_t)(row0 + r) * N + col] = f2bf(ov);
        }
      } else {
        #pragma unroll
        for (int r = 0; r < 4; ++r) {
          float v = acc[m][n][r];
          if (OUT_BF16) ((ushort_t*)Cv)[(size_t)(row0 + r) * N + col] = f2bf(v);
          else          ((float*)Cv)[(size_t)(row0 + r) * N + col] = v;
        }
      }
    }
  }
}

// merged QKV projection (single-buffer, 24KB LDS -> target 4 blocks/CU)
__global__ __launch_bounds__(512, 8)
void k_gemm_qkv(const ushort_t* __restrict__ xb,
                const ushort_t* __restrict__ WqT, const ushort_t* __restrict__ WkT,
                const ushort_t* __restrict__ WvT,
                ushort_t* __restrict__ qb, ushort_t* __restrict__ kb,
                ushort_t* __restrict__ vT,
                const float* __restrict__ fc, const float* __restrict__ fs) {
  const int sel = blockIdx.y;
  const ushort_t* A  = (sel == 2) ? WvT : xb;
  const ushort_t* Bt = (sel == 0) ? WqT : (sel == 1) ? WkT : xb;
  ushort_t* C = (sel == 0) ? qb : (sel == 1) ? kb : vT;
  gemm_core<true, true>(A, Bt, C, 4096, 4096, 4096, sel < 2, fc, fs,
                        blockIdx.x, gridDim.x);
}

// single GEMM (Wo): fp32 out, double-buffered (only 2 resident at grid 512)
__global__ __launch_bounds__(512, 4)
void k_gemm_wo(const ushort_t* __restrict__ A, const ushort_t* __restrict__ Bt,
               float* __restrict__ C) {
  gemm_core<false, false>(A, Bt, C, 4096, 4096, 4096, false, nullptr, nullptr,
                          blockIdx.x, gridDim.x);
}

// ---------------- causal flash attention, QBLK=128, 8 waves ----------------
// Double-buffered DMA staging, counted vmcnt(4); XCD-grouped swizzle; defer-max.
__global__ __launch_bounds__(512, 2)
void k_attn(const ushort_t* __restrict__ Q, const ushort_t* __restrict__ Kb,
            const ushort_t* __restrict__ Vt, ushort_t* __restrict__ Y) {
  __shared__ __align__(16) ushort_t Ks[2][64 * 128];
  __shared__ __align__(16) ushort_t Vs[2][128 * 64];
  __shared__ __align__(16) ushort_t Ps[8][16 * 64];
  const int id = blockIdx.x;
  const int xcd = id & 7, slot = id >> 3;
  const int bx = slot & 7, gHi = slot >> 3;
  const int g = gHi * 8 + xcd;
  const int h = g & 31, b = g >> 5;
  const int tid = threadIdx.x;
  const int w = tid >> 6, l = tid & 63;
  const int lg = l >> 4, lc = l & 15;
  const float scale = 0.08838834764831845f;  // 1/sqrt(128)
  const float THR = 8.0f;

  auto stageKV = [&](int kv0, int buf) {
    #pragma unroll
    for (int i = 0; i < 2; ++i) {
      int seg = w * 2 + i;
      {
        int row = seg * 4 + (l >> 4);
        int csrc = (l & 15) ^ (row & 7);
        gload_lds16(Kb + (size_t)(b * TSEQ + kv0 + row) * DMODEL + h * 128 + csrc * 8,
                    &Ks[buf][seg * 512]);
      }
      {
        int row = seg * 8 + (l >> 3);
        int csrc = (l & 7) ^ (l >> 3);
        gload_lds16(Vt + (size_t)(h * 128 + row) * DMODEL + b * TSEQ + kv0 + csrc * 8,
                    &Vs[buf][seg * 512]);
      }
    }
  };

  for (int qi = 0; qi < 2; ++qi) {
    const int qt = qi ? (15 - bx) : bx;
    const int q0 = qt * 128;
    const int wrow0 = q0 + w * 16;

    bf16x8 qf[4];
    {
      const ushort_t* qp = Q + (size_t)(b * TSEQ + wrow0 + lc) * DMODEL + h * 128;
      #pragma unroll
      for (int ks = 0; ks < 4; ++ks) qf[ks] = *(const bf16x8*)(qp + ks * 32 + lg * 8);
    }

    float m_r[4], lp[4];
    #pragma unroll
    for (int r = 0; r < 4; ++r) { m_r[r] = -1e30f; lp[r] = 0.f; }
    f32x4 o[8];
    #pragma unroll
    for (int t = 0; t < 8; ++t) o[t] = (f32x4){0.f, 0.f, 0.f, 0.f};

    const int nkv = (qt + 1) * 2;
    stageKV(0, 0);
    for (int kt = 0; kt < nkv; ++kt) {
      const int cur = kt & 1;
      const int kv0 = kt * 64;
      if (kt + 1 < nkv) {
        stageKV((kt + 1) * 64, cur ^ 1);
        asm volatile("s_waitcnt vmcnt(4)" ::: "memory");
      } else {
        asm volatile("s_waitcnt vmcnt(0)" ::: "memory");
      }
      __builtin_amdgcn_s_barrier();

      if (kv0 <= wrow0 + 15) {
        f32x4 s[4];
        #pragma unroll
        for (int n = 0; n < 4; ++n) s[n] = (f32x4){0.f, 0.f, 0.f, 0.f};
        __builtin_amdgcn_s_setprio(1);
        #pragma unroll
        for (int ks = 0; ks < 4; ++ks)
          #pragma unroll
          for (int n = 0; n < 4; ++n) {
            int row = n * 16 + lc;
            bf16x8 kf = *(const bf16x8*)&Ks[cur][row * 128 + ((ks * 32 + lg * 8) ^ ((row & 7) * 8))];
            s[n] = __builtin_amdgcn_mfma_f32_16x16x32_bf16(qf[ks], kf, s[n], 0, 0, 0);
          }
        __builtin_amdgcn_s_setprio(0);

        float sv[4][4];
        if (kv0 + 63 > wrow0) {
          #pragma unroll
          for (int n = 0; n < 4; ++n)
            #pragma unroll
            for (int r = 0; r < 4; ++r) {
              float x = s[n][r] * scale;
              int kvg = kv0 + n * 16 + lc;
              int qg = wrow0 + lg * 4 + r;
              sv[n][r] = (kvg > qg) ? -1e30f : x;
            }
        } else {
          #pragma unroll
          for (int n = 0; n < 4; ++n)
            #pragma unroll
            for (int r = 0; r < 4; ++r) sv[n][r] = s[n][r] * scale;
        }

        float pmax[4];
        #pragma unroll
        for (int r = 0; r < 4; ++r)
          pmax[r] = fmaxf(fmaxf(sv[0][r], sv[1][r]), fmaxf(sv[2][r], sv[3][r]));
        bool ok = (pmax[0] <= m_r[0] + THR) && (pmax[1] <= m_r[1] + THR) &&
                  (pmax[2] <= m_r[2] + THR) && (pmax[3] <= m_r[3] + THR);
        if (!__all(ok)) {
          #pragma unroll
          for (int r = 0; r < 4; ++r) {
            float mx = pmax[r];
            #pragma unroll
            for (int off = 1; off < 16; off <<= 1) mx = fmaxf(mx, __shfl_xor(mx, off, 16));
            float mn = fmaxf(m_r[r], mx);
            float al = __expf(m_r[r] - mn);
            m_r[r] = mn;
            lp[r] *= al;
            #pragma unroll
            for (int t = 0; t < 8; ++t) o[t][r] *= al;
          }
        }

        #pragma unroll
        for (int n = 0; n < 4; ++n)
          #pragma unroll
          for (int r = 0; r < 4; ++r) {
            float p = __expf(sv[n][r] - m_r[r]);
            lp[r] += p;
            int row = lg * 4 + r, col = n * 16 + lc;
            Ps[w][row * 64 + (col ^ (lg * 16))] = f2bf(p);
          }

        __builtin_amdgcn_s_setprio(1);
        #pragma unroll
        for (int kvs = 0; kvs < 2; ++kvs) {
          bf16x8 pa = *(const bf16x8*)&Ps[w][lc * 64 + ((kvs * 32 + lg * 8) ^ ((lc >> 2) * 16))];
          #pragma unroll
          for (int t = 0; t < 8; ++t) {
            int vrow = t * 16 + lc;
            bf16x8 vb = *(const bf16x8*)&Vs[cur][vrow * 64 + ((kvs * 32 + lg * 8) ^ ((vrow & 7) * 8))];
            o[t] = __builtin_amdgcn_mfma_f32_16x16x32_bf16(pa, vb, o[t], 0, 0, 0);
          }
        }
        __builtin_amdgcn_s_setprio(0);
      }
      asm volatile("" ::: "memory");
      __builtin_amdgcn_s_barrier();
    }

    float linv[4];
    #pragma unroll
    for (int r = 0; r < 4; ++r) {
      float ls = lp[r];
      #pragma unroll
      for (int off = 1; off < 16; off <<= 1) ls += __shfl_xor(ls, off, 16);
      linv[r] = 1.0f / ls;
    }

    #pragma unroll
    for (int t = 0; t < 8; ++t)
      #pragma unroll
      for (int r = 0; r < 4; ++r) {
        int row = wrow0 + lg * 4 + r;
        int col = h * 128 + t * 16 + lc;
        Y[(size_t)(b * TSEQ + row) * DMODEL + col] = f2bf(o[t][r] * linv[r]);
      }
  }
}

extern "C" void kernel_launch(void* const* d_in, const int* in_sizes, int n_in,
                              void* d_out, int out_size, void* d_ws, size_t ws_size,
                              hipStream_t stream) {
  const float* x  = (const float*)d_in[0];
  const float* fc = (const float*)d_in[1];
  const float* fs = (const float*)d_in[2];
  const float* Wq = (const float*)d_in[3];
  const float* Wk = (const float*)d_in[4];
  const float* Wv = (const float*)d_in[5];
  const float* Wo = (const float*)d_in[6];

  const size_t SZ = (size_t)4096 * 4096;
  ushort_t* xb  = (ushort_t*)d_ws;
  ushort_t* WqT = xb + SZ;
  ushort_t* WkT = WqT + SZ;
  ushort_t* WvT = WkT + SZ;
  ushort_t* WoT = WvT + SZ;
  ushort_t* qb  = WoT + SZ;
  ushort_t* kb  = qb + SZ;
  ushort_t* vT  = kb + SZ;
  ushort_t* yb  = vT + SZ;

  // prep: 4 weight transposes + x cast in one launch (z = 0..4)
  dim3 tg(64, 64, 5);
  k_prep<<<tg, 256, 0, stream>>>(Wq, Wk, Wv, Wo, x, WqT, xb);

  // merged Q,K,V^T projections: single-buffered, target 4 blocks/CU
  dim3 gq(512, 3);
  k_gemm_qkv<<<gq, 512, 0, stream>>>(xb, WqT, WkT, WvT, qb, kb, vT, fc, fs);

  k_attn<<<512, 512, 0, stream>>>(qb, kb, vT, yb);

  k_gemm_wo<<<512, 512, 0, stream>>>(yb, WoT, (float*)d_out);
}

// Round 18
// 4531.355 us; speedup vs baseline: 1.4025x; 1.4025x over previous
//
#include <hip/hip_runtime.h>

typedef unsigned short ushort_t;
typedef unsigned int uint32;

typedef float f32x4 __attribute__((ext_vector_type(4)));
typedef __bf16 bf16x8 __attribute__((ext_vector_type(8)));
typedef unsigned short us8 __attribute__((ext_vector_type(8)));
typedef unsigned short us4 __attribute__((ext_vector_type(4)));

#define TSEQ 2048
#define DMODEL 4096

__device__ __forceinline__ ushort_t f2bf(float f) {
  uint32 u = __builtin_bit_cast(uint32, f);
  u += 0x7FFFu + ((u >> 16) & 1u);   // RNE (no NaNs in this problem)
  return (ushort_t)(u >> 16);
}
__device__ __forceinline__ float bf2f(ushort_t u) {
  return __builtin_bit_cast(float, ((uint32)u) << 16);
}

__device__ __forceinline__ void gload_lds16(const void* g, void* l) {
  auto gp = (const __attribute__((address_space(1))) void*)g;
  auto lp = (__attribute__((address_space(3))) void*)l;
  __builtin_amdgcn_global_load_lds(gp, lp, 16, 0, 0);
}

// ---- prep: z=0..3 transpose+cast W_z (K x N fp32 -> N x K bf16); z=4 cast x ----
__global__ __launch_bounds__(256) void k_prep(const float* __restrict__ W0,
                                              const float* __restrict__ W1,
                                              const float* __restrict__ W2,
                                              const float* __restrict__ W3,
                                              const float* __restrict__ x,
                                              ushort_t* __restrict__ WTbase,
                                              ushort_t* __restrict__ xb) {
  const int tid = threadIdx.x;
  const int n0 = blockIdx.x * 64, k0 = blockIdx.y * 64;
  if (blockIdx.z == 4) {
    #pragma unroll
    for (int it = 0; it < 4; ++it) {
      int e = it * 256 + tid;
      int r = e >> 4, c4 = e & 15;
      float4 v = *(const float4*)(x + (size_t)(k0 + r) * DMODEL + n0 + c4 * 4);
      us4 o; o[0] = f2bf(v.x); o[1] = f2bf(v.y); o[2] = f2bf(v.z); o[3] = f2bf(v.w);
      *(us4*)(xb + (size_t)(k0 + r) * DMODEL + n0 + c4 * 4) = o;
    }
    return;
  }
  __shared__ __align__(16) ushort_t ts[64 * 72];
  const float* Ws[4] = {W0, W1, W2, W3};
  const float* W = Ws[blockIdx.z];
  ushort_t* WT = WTbase + (size_t)blockIdx.z * DMODEL * DMODEL;
  #pragma unroll
  for (int it = 0; it < 4; ++it) {
    int e = it * 256 + tid;
    int r = e >> 4, c4 = e & 15;
    float4 v = *(const float4*)(W + (size_t)(k0 + r) * DMODEL + n0 + c4 * 4);
    us4 o; o[0] = f2bf(v.x); o[1] = f2bf(v.y); o[2] = f2bf(v.z); o[3] = f2bf(v.w);
    *(us4*)&ts[r * 72 + c4 * 4] = o;
  }
  __syncthreads();
  #pragma unroll
  for (int it = 0; it < 4; ++it) {
    int e = it * 256 + tid;
    int r2 = e >> 4, c4 = e & 15;
    us4 o;
    #pragma unroll
    for (int j = 0; j < 4; ++j) o[j] = ts[(c4 * 4 + j) * 72 + r2];
    *(us4*)(WT + (size_t)(n0 + r2) * DMODEL + k0 + c4 * 4) = o;
  }
}

// ---------------- 128x256 GEMM core; SBUF=true: single-buffer 24KB (3 blocks/CU @ LB(512,6)),
// SBUF=false: double-buffer 48KB (2 blocks/CU, R15 measured-best) ----------------
template <bool OUT_BF16, bool SBUF>
__device__ __forceinline__
void gemm_core(const ushort_t* __restrict__ A, const ushort_t* __restrict__ Bt,
               void* __restrict__ Cv, int M, int N, int K, bool rope,
               const float* __restrict__ fc, const float* __restrict__ fs,
               int wgx, int nwgx) {
  __shared__ __align__(16) ushort_t As[SBUF ? 1 : 2][128 * 32];
  __shared__ __align__(16) ushort_t Bs[SBUF ? 1 : 2][256 * 32];
  const int tid = threadIdx.x;
  const int w = tid >> 6, l = tid & 63;
  const int wr = w >> 2, wc = w & 3;
  const int lg = l >> 4, lc = l & 15;

  // XCD-bijective swizzle over the x-extent (nwgx % 8 == 0)
  const int cpx = nwgx >> 3;
  const int wg = (wgx & 7) * cpx + (wgx >> 3);
  const int nbn = N >> 8;
  const int bm = wg / nbn, bn = wg % nbn;

  const ushort_t* Ab = A + (size_t)(bm * 128) * K;
  const ushort_t* Bb = Bt + (size_t)(bn * 256) * K;

  const int slotA = tid;
  const int rowA = slotA >> 2;
  const int chA = (slotA & 3) ^ (rowA & 3) ^ (2 * ((rowA >> 2) & 1));
  const ushort_t* gAp = Ab + (size_t)rowA * K + chA * 8;
  const int dstA = (w * 64) * 8;

  const int rowB0 = tid >> 2, rowB1 = (512 + tid) >> 2;
  const int chB0 = (tid & 3) ^ (rowB0 & 3) ^ (2 * ((rowB0 >> 2) & 1));
  const int chB1 = (tid & 3) ^ (rowB1 & 3) ^ (2 * ((rowB1 >> 2) & 1));
  const ushort_t* gBp0 = Bb + (size_t)rowB0 * K + chB0 * 8;
  const ushort_t* gBp1 = Bb + (size_t)rowB1 * K + chB1 * 8;
  const int dstB0 = (w * 64) * 8;
  const int dstB1 = (512 + w * 64) * 8;

  const int rswz = (lg ^ (lc & 3) ^ (2 * ((lc >> 2) & 1))) * 8;
  int offA[4], offB[4];
  #pragma unroll
  for (int m = 0; m < 4; ++m) offA[m] = (wr * 64 + m * 16 + lc) * 32 + rswz;
  #pragma unroll
  for (int n = 0; n < 4; ++n) offB[n] = (wc * 64 + n * 16 + lc) * 32 + rswz;

  f32x4 acc[4][4];
  #pragma unroll
  for (int m = 0; m < 4; ++m)
    #pragma unroll
    for (int n = 0; n < 4; ++n) acc[m][n] = (f32x4){0.f, 0.f, 0.f, 0.f};

  const int NT = K >> 5;
  auto stage = [&](int t, int buf) {
    const int k0 = t << 5;
    gload_lds16(gAp + k0, &As[buf][dstA]);
    gload_lds16(gBp0 + k0, &Bs[buf][dstB0]);
    gload_lds16(gBp1 + k0, &Bs[buf][dstB1]);
  };

  if (SBUF) {
    // m97 2-barrier pattern: bar -> stage -> vmcnt(0) -> bar -> compute.
    // 3 co-resident blocks' MFMA covers the drain (TLP).
    for (int t = 0; t < NT; ++t) {
      if (t > 0) {
        asm volatile("" ::: "memory");
        __builtin_amdgcn_s_barrier();   // reads of tile t-1 complete
      }
      stage(t, 0);
      asm volatile("s_waitcnt vmcnt(0)" ::: "memory");
      __builtin_amdgcn_s_barrier();

      bf16x8 af[4], bfv[4];
      #pragma unroll
      for (int m = 0; m < 4; ++m) af[m] = *(const bf16x8*)&As[0][offA[m]];
      #pragma unroll
      for (int n = 0; n < 4; ++n) bfv[n] = *(const bf16x8*)&Bs[0][offB[n]];
      __builtin_amdgcn_s_setprio(1);
      #pragma unroll
      for (int m = 0; m < 4; ++m)
        #pragma unroll
        for (int n = 0; n < 4; ++n)
          acc[m][n] = __builtin_amdgcn_mfma_f32_16x16x32_bf16(af[m], bfv[n], acc[m][n], 0, 0, 0);
      __builtin_amdgcn_s_setprio(0);
    }
  } else {
    stage(0, 0);
    asm volatile("s_waitcnt vmcnt(0)" ::: "memory");
    __builtin_amdgcn_s_barrier();

    for (int t = 0; t < NT; ++t) {
      const int cur = t & 1;
      if (t + 1 < NT) stage(t + 1, cur ^ 1);

      bf16x8 af[4], bfv[4];
      #pragma unroll
      for (int m = 0; m < 4; ++m) af[m] = *(const bf16x8*)&As[cur][offA[m]];
      #pragma unroll
      for (int n = 0; n < 4; ++n) bfv[n] = *(const bf16x8*)&Bs[cur][offB[n]];
      __builtin_amdgcn_s_setprio(1);
      #pragma unroll
      for (int m = 0; m < 4; ++m)
        #pragma unroll
        for (int n = 0; n < 4; ++n)
          acc[m][n] = __builtin_amdgcn_mfma_f32_16x16x32_bf16(af[m], bfv[n], acc[m][n], 0, 0, 0);
      __builtin_amdgcn_s_setprio(0);

      if (t + 1 < NT) {
        asm volatile("s_waitcnt vmcnt(0)" ::: "memory");
        __builtin_amdgcn_s_barrier();
      }
    }
  }

  #pragma unroll
  for (int m = 0; m < 4; ++m) {
    int row0 = bm * 128 + wr * 64 + m * 16 + lg * 4;
    #pragma unroll
    for (int n = 0; n < 4; ++n) {
      int col = bn * 256 + wc * 64 + n * 16 + lc;
      if (rope) {
        int i0 = (col & 127) >> 1;
        #pragma unroll
        for (int r = 0; r < 4; ++r) {
          int tt = (row0 + r) & (TSEQ - 1);
          float c = fc[tt * 64 + i0];
          float s = fs[tt * 64 + i0];
          float v = acc[m][n][r];
          float p = __shfl_xor(v, 1);
          float ov = (lc & 1) ? (p * s + v * c) : (v * c - p * s);
          ((ushort_t*)Cv)[(size_t)(row0 + r) * N + col] = f2bf(ov);
        }
      } else {
        #pragma unroll
        for (int r = 0; r < 4; ++r) {
          float v = acc[m][n][r];
          if (OUT_BF16) ((ushort_t*)Cv)[(size_t)(row0 + r) * N + col] = f2bf(v);
          else          ((float*)Cv)[(size_t)(row0 + r) * N + col] = v;
        }
      }
    }
  }
}

// merged QKV projection (single-buffer 24KB; LB(512,6) -> VGPR budget 85, 3 blocks/CU)
__global__ __launch_bounds__(512, 6)
void k_gemm_qkv(const ushort_t* __restrict__ xb,
                const ushort_t* __restrict__ WqT, const ushort_t* __restrict__ WkT,
                const ushort_t* __restrict__ WvT,
                ushort_t* __restrict__ qb, ushort_t* __restrict__ kb,
                ushort_t* __restrict__ vT,
                const float* __restrict__ fc, const float* __restrict__ fs) {
  const int sel = blockIdx.y;
  const ushort_t* A  = (sel == 2) ? WvT : xb;
  const ushort_t* Bt = (sel == 0) ? WqT : (sel == 1) ? WkT : xb;
  ushort_t* C = (sel == 0) ? qb : (sel == 1) ? kb : vT;
  gemm_core<true, true>(A, Bt, C, 4096, 4096, 4096, sel < 2, fc, fs,
                        blockIdx.x, gridDim.x);
}

// single GEMM (Wo): fp32 out, double-buffered (only 2 resident at grid 512)
__global__ __launch_bounds__(512, 4)
void k_gemm_wo(const ushort_t* __restrict__ A, const ushort_t* __restrict__ Bt,
               float* __restrict__ C) {
  gemm_core<false, false>(A, Bt, C, 4096, 4096, 4096, false, nullptr, nullptr,
                          blockIdx.x, gridDim.x);
}

// ---------------- causal flash attention, QBLK=128, 8 waves ----------------
// Double-buffered DMA staging, counted vmcnt(4); XCD-grouped swizzle; defer-max.
__global__ __launch_bounds__(512, 2)
void k_attn(const ushort_t* __restrict__ Q, const ushort_t* __restrict__ Kb,
            const ushort_t* __restrict__ Vt, ushort_t* __restrict__ Y) {
  __shared__ __align__(16) ushort_t Ks[2][64 * 128];
  __shared__ __align__(16) ushort_t Vs[2][128 * 64];
  __shared__ __align__(16) ushort_t Ps[8][16 * 64];
  const int id = blockIdx.x;
  const int xcd = id & 7, slot = id >> 3;
  const int bx = slot & 7, gHi = slot >> 3;
  const int g = gHi * 8 + xcd;
  const int h = g & 31, b = g >> 5;
  const int tid = threadIdx.x;
  const int w = tid >> 6, l = tid & 63;
  const int lg = l >> 4, lc = l & 15;
  const float scale = 0.08838834764831845f;  // 1/sqrt(128)
  const float THR = 8.0f;

  auto stageKV = [&](int kv0, int buf) {
    #pragma unroll
    for (int i = 0; i < 2; ++i) {
      int seg = w * 2 + i;
      {
        int row = seg * 4 + (l >> 4);
        int csrc = (l & 15) ^ (row & 7);
        gload_lds16(Kb + (size_t)(b * TSEQ + kv0 + row) * DMODEL + h * 128 + csrc * 8,
                    &Ks[buf][seg * 512]);
      }
      {
        int row = seg * 8 + (l >> 3);
        int csrc = (l & 7) ^ (l >> 3);
        gload_lds16(Vt + (size_t)(h * 128 + row) * DMODEL + b * TSEQ + kv0 + csrc * 8,
                    &Vs[buf][seg * 512]);
      }
    }
  };

  for (int qi = 0; qi < 2; ++qi) {
    const int qt = qi ? (15 - bx) : bx;
    const int q0 = qt * 128;
    const int wrow0 = q0 + w * 16;

    bf16x8 qf[4];
    {
      const ushort_t* qp = Q + (size_t)(b * TSEQ + wrow0 + lc) * DMODEL + h * 128;
      #pragma unroll
      for (int ks = 0; ks < 4; ++ks) qf[ks] = *(const bf16x8*)(qp + ks * 32 + lg * 8);
    }

    float m_r[4], lp[4];
    #pragma unroll
    for (int r = 0; r < 4; ++r) { m_r[r] = -1e30f; lp[r] = 0.f; }
    f32x4 o[8];
    #pragma unroll
    for (int t = 0; t < 8; ++t) o[t] = (f32x4){0.f, 0.f, 0.f, 0.f};

    const int nkv = (qt + 1) * 2;
    stageKV(0, 0);
    for (int kt = 0; kt < nkv; ++kt) {
      const int cur = kt & 1;
      const int kv0 = kt * 64;
      if (kt + 1 < nkv) {
        stageKV((kt + 1) * 64, cur ^ 1);
        asm volatile("s_waitcnt vmcnt(4)" ::: "memory");
      } else {
        asm volatile("s_waitcnt vmcnt(0)" ::: "memory");
      }
      __builtin_amdgcn_s_barrier();

      if (kv0 <= wrow0 + 15) {
        f32x4 s[4];
        #pragma unroll
        for (int n = 0; n < 4; ++n) s[n] = (f32x4){0.f, 0.f, 0.f, 0.f};
        __builtin_amdgcn_s_setprio(1);
        #pragma unroll
        for (int ks = 0; ks < 4; ++ks)
          #pragma unroll
          for (int n = 0; n < 4; ++n) {
            int row = n * 16 + lc;
            bf16x8 kf = *(const bf16x8*)&Ks[cur][row * 128 + ((ks * 32 + lg * 8) ^ ((row & 7) * 8))];
            s[n] = __builtin_amdgcn_mfma_f32_16x16x32_bf16(qf[ks], kf, s[n], 0, 0, 0);
          }
        __builtin_amdgcn_s_setprio(0);

        float sv[4][4];
        if (kv0 + 63 > wrow0) {
          #pragma unroll
          for (int n = 0; n < 4; ++n)
            #pragma unroll
            for (int r = 0; r < 4; ++r) {
              float x = s[n][r] * scale;
              int kvg = kv0 + n * 16 + lc;
              int qg = wrow0 + lg * 4 + r;
              sv[n][r] = (kvg > qg) ? -1e30f : x;
            }
        } else {
          #pragma unroll
          for (int n = 0; n < 4; ++n)
            #pragma unroll
            for (int r = 0; r < 4; ++r) sv[n][r] = s[n][r] * scale;
        }

        float pmax[4];
        #pragma unroll
        for (int r = 0; r < 4; ++r)
          pmax[r] = fmaxf(fmaxf(sv[0][r], sv[1][r]), fmaxf(sv[2][r], sv[3][r]));
        bool ok = (pmax[0] <= m_r[0] + THR) && (pmax[1] <= m_r[1] + THR) &&
                  (pmax[2] <= m_r[2] + THR) && (pmax[3] <= m_r[3] + THR);
        if (!__all(ok)) {
          #pragma unroll
          for (int r = 0; r < 4; ++r) {
            float mx = pmax[r];
            #pragma unroll
            for (int off = 1; off < 16; off <<= 1) mx = fmaxf(mx, __shfl_xor(mx, off, 16));
            float mn = fmaxf(m_r[r], mx);
            float al = __expf(m_r[r] - mn);
            m_r[r] = mn;
            lp[r] *= al;
            #pragma unroll
            for (int t = 0; t < 8; ++t) o[t][r] *= al;
          }
        }

        #pragma unroll
        for (int n = 0; n < 4; ++n)
          #pragma unroll
          for (int r = 0; r < 4; ++r) {
            float p = __expf(sv[n][r] - m_r[r]);
            lp[r] += p;
            int row = lg * 4 + r, col = n * 16 + lc;
            Ps[w][row * 64 + (col ^ (lg * 16))] = f2bf(p);
          }

        __builtin_amdgcn_s_setprio(1);
        #pragma unroll
        for (int kvs = 0; kvs < 2; ++kvs) {
          bf16x8 pa = *(const bf16x8*)&Ps[w][lc * 64 + ((kvs * 32 + lg * 8) ^ ((lc >> 2) * 16))];
          #pragma unroll
          for (int t = 0; t < 8; ++t) {
            int vrow = t * 16 + lc;
            bf16x8 vb = *(const bf16x8*)&Vs[cur][vrow * 64 + ((kvs * 32 + lg * 8) ^ ((vrow & 7) * 8))];
            o[t] = __builtin_amdgcn_mfma_f32_16x16x32_bf16(pa, vb, o[t], 0, 0, 0);
          }
        }
        __builtin_amdgcn_s_setprio(0);
      }
      asm volatile("" ::: "memory");
      __builtin_amdgcn_s_barrier();
    }

    float linv[4];
    #pragma unroll
    for (int r = 0; r < 4; ++r) {
      float ls = lp[r];
      #pragma unroll
      for (int off = 1; off < 16; off <<= 1) ls += __shfl_xor(ls, off, 16);
      linv[r] = 1.0f / ls;
    }

    #pragma unroll
    for (int t = 0; t < 8; ++t)
      #pragma unroll
      for (int r = 0; r < 4; ++r) {
        int row = wrow0 + lg * 4 + r;
        int col = h * 128 + t * 16 + lc;
        Y[(size_t)(b * TSEQ + row) * DMODEL + col] = f2bf(o[t][r] * linv[r]);
      }
  }
}

extern "C" void kernel_launch(void* const* d_in, const int* in_sizes, int n_in,
                              void* d_out, int out_size, void* d_ws, size_t ws_size,
                              hipStream_t stream) {
  const float* x  = (const float*)d_in[0];
  const float* fc = (const float*)d_in[1];
  const float* fs = (const float*)d_in[2];
  const float* Wq = (const float*)d_in[3];
  const float* Wk = (const float*)d_in[4];
  const float* Wv = (const float*)d_in[5];
  const float* Wo = (const float*)d_in[6];

  const size_t SZ = (size_t)4096 * 4096;
  ushort_t* xb  = (ushort_t*)d_ws;
  ushort_t* WqT = xb + SZ;
  ushort_t* WkT = WqT + SZ;
  ushort_t* WvT = WkT + SZ;
  ushort_t* WoT = WvT + SZ;
  ushort_t* qb  = WoT + SZ;
  ushort_t* kb  = qb + SZ;
  ushort_t* vT  = kb + SZ;
  ushort_t* yb  = vT + SZ;

  // prep: 4 weight transposes + x cast in one launch (z = 0..4)
  dim3 tg(64, 64, 5);
  k_prep<<<tg, 256, 0, stream>>>(Wq, Wk, Wv, Wo, x, WqT, xb);

  // merged Q,K,V^T projections: single-buffered, LB(512,6) -> 3 blocks/CU
  dim3 gq(512, 3);
  k_gemm_qkv<<<gq, 512, 0, stream>>>(xb, WqT, WkT, WvT, qb, kb, vT, fc, fs);

  k_attn<<<512, 512, 0, stream>>>(qb, kb, vT, yb);

  k_gemm_wo<<<512, 512, 0, stream>>>(yb, WoT, (float*)d_out);
}

// Round 19
// 781.628 us; speedup vs baseline: 8.1306x; 5.7973x over previous
//
#include <hip/hip_runtime.h>

typedef unsigned short ushort_t;
typedef unsigned int uint32;

typedef float f32x4 __attribute__((ext_vector_type(4)));
typedef __bf16 bf16x8 __attribute__((ext_vector_type(8)));
typedef unsigned short us8 __attribute__((ext_vector_type(8)));
typedef unsigned short us4 __attribute__((ext_vector_type(4)));

#define TSEQ 2048
#define DMODEL 4096

__device__ __forceinline__ ushort_t f2bf(float f) {
  uint32 u = __builtin_bit_cast(uint32, f);
  u += 0x7FFFu + ((u >> 16) & 1u);   // RNE (no NaNs in this problem)
  return (ushort_t)(u >> 16);
}
__device__ __forceinline__ float bf2f(ushort_t u) {
  return __builtin_bit_cast(float, ((uint32)u) << 16);
}

__device__ __forceinline__ void gload_lds16(const void* g, void* l) {
  auto gp = (const __attribute__((address_space(1))) void*)g;
  auto lp = (__attribute__((address_space(3))) void*)l;
  __builtin_amdgcn_global_load_lds(gp, lp, 16, 0, 0);
}

// ---- prep: z=0..3 transpose+cast W_z (K x N fp32 -> N x K bf16); z=4 cast x ----
__global__ __launch_bounds__(256) void k_prep(const float* __restrict__ W0,
                                              const float* __restrict__ W1,
                                              const float* __restrict__ W2,
                                              const float* __restrict__ W3,
                                              const float* __restrict__ x,
                                              ushort_t* __restrict__ WTbase,
                                              ushort_t* __restrict__ xb) {
  const int tid = threadIdx.x;
  const int n0 = blockIdx.x * 64, k0 = blockIdx.y * 64;
  if (blockIdx.z == 4) {
    #pragma unroll
    for (int it = 0; it < 4; ++it) {
      int e = it * 256 + tid;
      int r = e >> 4, c4 = e & 15;
      float4 v = *(const float4*)(x + (size_t)(k0 + r) * DMODEL + n0 + c4 * 4);
      us4 o; o[0] = f2bf(v.x); o[1] = f2bf(v.y); o[2] = f2bf(v.z); o[3] = f2bf(v.w);
      *(us4*)(xb + (size_t)(k0 + r) * DMODEL + n0 + c4 * 4) = o;
    }
    return;
  }
  __shared__ __align__(16) ushort_t ts[64 * 72];
  const float* Ws[4] = {W0, W1, W2, W3};
  const float* W = Ws[blockIdx.z];
  ushort_t* WT = WTbase + (size_t)blockIdx.z * DMODEL * DMODEL;
  #pragma unroll
  for (int it = 0; it < 4; ++it) {
    int e = it * 256 + tid;
    int r = e >> 4, c4 = e & 15;
    float4 v = *(const float4*)(W + (size_t)(k0 + r) * DMODEL + n0 + c4 * 4);
    us4 o; o[0] = f2bf(v.x); o[1] = f2bf(v.y); o[2] = f2bf(v.z); o[3] = f2bf(v.w);
    *(us4*)&ts[r * 72 + c4 * 4] = o;
  }
  __syncthreads();
  #pragma unroll
  for (int it = 0; it < 4; ++it) {
    int e = it * 256 + tid;
    int r2 = e >> 4, c4 = e & 15;
    us4 o;
    #pragma unroll
    for (int j = 0; j < 4; ++j) o[j] = ts[(c4 * 4 + j) * 72 + r2];
    *(us4*)(WT + (size_t)(n0 + r2) * DMODEL + k0 + c4 * 4) = o;
  }
}

// ---------------- 128x256 GEMM core (R13/R15/R16 structure, measured best) ----------------
// BK=32, 8 waves 2x4, wave tile 64x64. LDS 48KB double-buffered -> 2 blocks/CU.
// 1 barrier + 1 vmcnt(0) per K-tile; co-resident block's MFMA covers the drain.
template <bool OUT_BF16>
__device__ __forceinline__
void gemm_core(const ushort_t* __restrict__ A, const ushort_t* __restrict__ Bt,
               void* __restrict__ Cv, int M, int N, int K, bool rope,
               const float* __restrict__ fc, const float* __restrict__ fs,
               int wgx, int nwgx) {
  __shared__ __align__(16) ushort_t As[2][128 * 32];
  __shared__ __align__(16) ushort_t Bs[2][256 * 32];
  const int tid = threadIdx.x;
  const int w = tid >> 6, l = tid & 63;
  const int wr = w >> 2, wc = w & 3;
  const int lg = l >> 4, lc = l & 15;

  // XCD-bijective swizzle over the x-extent (nwgx % 8 == 0)
  const int cpx = nwgx >> 3;
  const int wg = (wgx & 7) * cpx + (wgx >> 3);
  const int nbn = N >> 8;
  const int bm = wg / nbn, bn = wg % nbn;

  const ushort_t* Ab = A + (size_t)(bm * 128) * K;
  const ushort_t* Bb = Bt + (size_t)(bn * 256) * K;

  const int slotA = tid;
  const int rowA = slotA >> 2;
  const int chA = (slotA & 3) ^ (rowA & 3) ^ (2 * ((rowA >> 2) & 1));
  const ushort_t* gAp = Ab + (size_t)rowA * K + chA * 8;
  const int dstA = (w * 64) * 8;

  const int rowB0 = tid >> 2, rowB1 = (512 + tid) >> 2;
  const int chB0 = (tid & 3) ^ (rowB0 & 3) ^ (2 * ((rowB0 >> 2) & 1));
  const int chB1 = (tid & 3) ^ (rowB1 & 3) ^ (2 * ((rowB1 >> 2) & 1));
  const ushort_t* gBp0 = Bb + (size_t)rowB0 * K + chB0 * 8;
  const ushort_t* gBp1 = Bb + (size_t)rowB1 * K + chB1 * 8;
  const int dstB0 = (w * 64) * 8;
  const int dstB1 = (512 + w * 64) * 8;

  const int rswz = (lg ^ (lc & 3) ^ (2 * ((lc >> 2) & 1))) * 8;
  int offA[4], offB[4];
  #pragma unroll
  for (int m = 0; m < 4; ++m) offA[m] = (wr * 64 + m * 16 + lc) * 32 + rswz;
  #pragma unroll
  for (int n = 0; n < 4; ++n) offB[n] = (wc * 64 + n * 16 + lc) * 32 + rswz;

  f32x4 acc[4][4];
  #pragma unroll
  for (int m = 0; m < 4; ++m)
    #pragma unroll
    for (int n = 0; n < 4; ++n) acc[m][n] = (f32x4){0.f, 0.f, 0.f, 0.f};

  const int NT = K >> 5;
  auto stage = [&](int t, int buf) {
    const int k0 = t << 5;
    gload_lds16(gAp + k0, &As[buf][dstA]);
    gload_lds16(gBp0 + k0, &Bs[buf][dstB0]);
    gload_lds16(gBp1 + k0, &Bs[buf][dstB1]);
  };

  stage(0, 0);
  asm volatile("s_waitcnt vmcnt(0)" ::: "memory");
  __builtin_amdgcn_s_barrier();

  for (int t = 0; t < NT; ++t) {
    const int cur = t & 1;
    if (t + 1 < NT) stage(t + 1, cur ^ 1);

    bf16x8 af[4], bfv[4];
    #pragma unroll
    for (int m = 0; m < 4; ++m) af[m] = *(const bf16x8*)&As[cur][offA[m]];
    #pragma unroll
    for (int n = 0; n < 4; ++n) bfv[n] = *(const bf16x8*)&Bs[cur][offB[n]];
    __builtin_amdgcn_s_setprio(1);
    #pragma unroll
    for (int m = 0; m < 4; ++m)
      #pragma unroll
      for (int n = 0; n < 4; ++n)
        acc[m][n] = __builtin_amdgcn_mfma_f32_16x16x32_bf16(af[m], bfv[n], acc[m][n], 0, 0, 0);
    __builtin_amdgcn_s_setprio(0);

    if (t + 1 < NT) {
      asm volatile("s_waitcnt vmcnt(0)" ::: "memory");
      __builtin_amdgcn_s_barrier();
    }
  }

  #pragma unroll
  for (int m = 0; m < 4; ++m) {
    int row0 = bm * 128 + wr * 64 + m * 16 + lg * 4;
    #pragma unroll
    for (int n = 0; n < 4; ++n) {
      int col = bn * 256 + wc * 64 + n * 16 + lc;
      if (rope) {
        int i0 = (col & 127) >> 1;
        #pragma unroll
        for (int r = 0; r < 4; ++r) {
          int tt = (row0 + r) & (TSEQ - 1);
          float c = fc[tt * 64 + i0];
          float s = fs[tt * 64 + i0];
          float v = acc[m][n][r];
          float p = __shfl_xor(v, 1);
          float ov = (lc & 1) ? (p * s + v * c) : (v * c - p * s);
          ((ushort_t*)Cv)[(size_t)(row0 + r) * N + col] = f2bf(ov);
        }
      } else {
        #pragma unroll
        for (int r = 0; r < 4; ++r) {
          float v = acc[m][n][r];
          if (OUT_BF16) ((ushort_t*)Cv)[(size_t)(row0 + r) * N + col] = f2bf(v);
          else          ((float*)Cv)[(size_t)(row0 + r) * N + col] = v;
        }
      }
    }
  }
}

// merged QKV projection: blockIdx.y selects {Q, K, V^T}
__global__ __launch_bounds__(512, 4)
void k_gemm_qkv(const ushort_t* __restrict__ xb,
                const ushort_t* __restrict__ WqT, const ushort_t* __restrict__ WkT,
                const ushort_t* __restrict__ WvT,
                ushort_t* __restrict__ qb, ushort_t* __restrict__ kb,
                ushort_t* __restrict__ vT,
                const float* __restrict__ fc, const float* __restrict__ fs) {
  const int sel = blockIdx.y;
  const ushort_t* A  = (sel == 2) ? WvT : xb;
  const ushort_t* Bt = (sel == 0) ? WqT : (sel == 1) ? WkT : xb;
  ushort_t* C = (sel == 0) ? qb : (sel == 1) ? kb : vT;
  gemm_core<true>(A, Bt, C, 4096, 4096, 4096, sel < 2, fc, fs, blockIdx.x, gridDim.x);
}

// single GEMM (Wo): fp32 out
__global__ __launch_bounds__(512, 4)
void k_gemm_wo(const ushort_t* __restrict__ A, const ushort_t* __restrict__ Bt,
               float* __restrict__ C) {
  gemm_core<false>(A, Bt, C, 4096, 4096, 4096, false, nullptr, nullptr,
                   blockIdx.x, gridDim.x);
}

// ---------------- causal flash attention, QBLK=128, 8 waves ----------------
// Double-buffered DMA staging, counted vmcnt(4); XCD-grouped swizzle; defer-max.
__global__ __launch_bounds__(512, 2)
void k_attn(const ushort_t* __restrict__ Q, const ushort_t* __restrict__ Kb,
            const ushort_t* __restrict__ Vt, ushort_t* __restrict__ Y) {
  __shared__ __align__(16) ushort_t Ks[2][64 * 128];
  __shared__ __align__(16) ushort_t Vs[2][128 * 64];
  __shared__ __align__(16) ushort_t Ps[8][16 * 64];
  const int id = blockIdx.x;
  const int xcd = id & 7, slot = id >> 3;
  const int bx = slot & 7, gHi = slot >> 3;
  const int g = gHi * 8 + xcd;
  const int h = g & 31, b = g >> 5;
  const int tid = threadIdx.x;
  const int w = tid >> 6, l = tid & 63;
  const int lg = l >> 4, lc = l & 15;
  const float scale = 0.08838834764831845f;  // 1/sqrt(128)
  const float THR = 8.0f;

  auto stageKV = [&](int kv0, int buf) {
    #pragma unroll
    for (int i = 0; i < 2; ++i) {
      int seg = w * 2 + i;
      {
        int row = seg * 4 + (l >> 4);
        int csrc = (l & 15) ^ (row & 7);
        gload_lds16(Kb + (size_t)(b * TSEQ + kv0 + row) * DMODEL + h * 128 + csrc * 8,
                    &Ks[buf][seg * 512]);
      }
      {
        int row = seg * 8 + (l >> 3);
        int csrc = (l & 7) ^ (l >> 3);
        gload_lds16(Vt + (size_t)(h * 128 + row) * DMODEL + b * TSEQ + kv0 + csrc * 8,
                    &Vs[buf][seg * 512]);
      }
    }
  };

  for (int qi = 0; qi < 2; ++qi) {
    const int qt = qi ? (15 - bx) : bx;
    const int q0 = qt * 128;
    const int wrow0 = q0 + w * 16;

    bf16x8 qf[4];
    {
      const ushort_t* qp = Q + (size_t)(b * TSEQ + wrow0 + lc) * DMODEL + h * 128;
      #pragma unroll
      for (int ks = 0; ks < 4; ++ks) qf[ks] = *(const bf16x8*)(qp + ks * 32 + lg * 8);
    }

    float m_r[4], lp[4];
    #pragma unroll
    for (int r = 0; r < 4; ++r) { m_r[r] = -1e30f; lp[r] = 0.f; }
    f32x4 o[8];
    #pragma unroll
    for (int t = 0; t < 8; ++t) o[t] = (f32x4){0.f, 0.f, 0.f, 0.f};

    const int nkv = (qt + 1) * 2;
    stageKV(0, 0);
    for (int kt = 0; kt < nkv; ++kt) {
      const int cur = kt & 1;
      const int kv0 = kt * 64;
      if (kt + 1 < nkv) {
        stageKV((kt + 1) * 64, cur ^ 1);
        asm volatile("s_waitcnt vmcnt(4)" ::: "memory");
      } else {
        asm volatile("s_waitcnt vmcnt(0)" ::: "memory");
      }
      __builtin_amdgcn_s_barrier();

      if (kv0 <= wrow0 + 15) {
        f32x4 s[4];
        #pragma unroll
        for (int n = 0; n < 4; ++n) s[n] = (f32x4){0.f, 0.f, 0.f, 0.f};
        __builtin_amdgcn_s_setprio(1);
        #pragma unroll
        for (int ks = 0; ks < 4; ++ks)
          #pragma unroll
          for (int n = 0; n < 4; ++n) {
            int row = n * 16 + lc;
            bf16x8 kf = *(const bf16x8*)&Ks[cur][row * 128 + ((ks * 32 + lg * 8) ^ ((row & 7) * 8))];
            s[n] = __builtin_amdgcn_mfma_f32_16x16x32_bf16(qf[ks], kf, s[n], 0, 0, 0);
          }
        __builtin_amdgcn_s_setprio(0);

        float sv[4][4];
        if (kv0 + 63 > wrow0) {
          #pragma unroll
          for (int n = 0; n < 4; ++n)
            #pragma unroll
            for (int r = 0; r < 4; ++r) {
              float x = s[n][r] * scale;
              int kvg = kv0 + n * 16 + lc;
              int qg = wrow0 + lg * 4 + r;
              sv[n][r] = (kvg > qg) ? -1e30f : x;
            }
        } else {
          #pragma unroll
          for (int n = 0; n < 4; ++n)
            #pragma unroll
            for (int r = 0; r < 4; ++r) sv[n][r] = s[n][r] * scale;
        }

        float pmax[4];
        #pragma unroll
        for (int r = 0; r < 4; ++r)
          pmax[r] = fmaxf(fmaxf(sv[0][r], sv[1][r]), fmaxf(sv[2][r], sv[3][r]));
        bool ok = (pmax[0] <= m_r[0] + THR) && (pmax[1] <= m_r[1] + THR) &&
                  (pmax[2] <= m_r[2] + THR) && (pmax[3] <= m_r[3] + THR);
        if (!__all(ok)) {
          #pragma unroll
          for (int r = 0; r < 4; ++r) {
            float mx = pmax[r];
            #pragma unroll
            for (int off = 1; off < 16; off <<= 1) mx = fmaxf(mx, __shfl_xor(mx, off, 16));
            float mn = fmaxf(m_r[r], mx);
            float al = __expf(m_r[r] - mn);
            m_r[r] = mn;
            lp[r] *= al;
            #pragma unroll
            for (int t = 0; t < 8; ++t) o[t][r] *= al;
          }
        }

        #pragma unroll
        for (int n = 0; n < 4; ++n)
          #pragma unroll
          for (int r = 0; r < 4; ++r) {
            float p = __expf(sv[n][r] - m_r[r]);
            lp[r] += p;
            int row = lg * 4 + r, col = n * 16 + lc;
            Ps[w][row * 64 + (col ^ (lg * 16))] = f2bf(p);
          }

        __builtin_amdgcn_s_setprio(1);
        #pragma unroll
        for (int kvs = 0; kvs < 2; ++kvs) {
          bf16x8 pa = *(const bf16x8*)&Ps[w][lc * 64 + ((kvs * 32 + lg * 8) ^ ((lc >> 2) * 16))];
          #pragma unroll
          for (int t = 0; t < 8; ++t) {
            int vrow = t * 16 + lc;
            bf16x8 vb = *(const bf16x8*)&Vs[cur][vrow * 64 + ((kvs * 32 + lg * 8) ^ ((vrow & 7) * 8))];
            o[t] = __builtin_amdgcn_mfma_f32_16x16x32_bf16(pa, vb, o[t], 0, 0, 0);
          }
        }
        __builtin_amdgcn_s_setprio(0);
      }
      asm volatile("" ::: "memory");
      __builtin_amdgcn_s_barrier();
    }

    float linv[4];
    #pragma unroll
    for (int r = 0; r < 4; ++r) {
      float ls = lp[r];
      #pragma unroll
      for (int off = 1; off < 16; off <<= 1) ls += __shfl_xor(ls, off, 16);
      linv[r] = 1.0f / ls;
    }

    #pragma unroll
    for (int t = 0; t < 8; ++t)
      #pragma unroll
      for (int r = 0; r < 4; ++r) {
        int row = wrow0 + lg * 4 + r;
        int col = h * 128 + t * 16 + lc;
        Y[(size_t)(b * TSEQ + row) * DMODEL + col] = f2bf(o[t][r] * linv[r]);
      }
  }
}

extern "C" void kernel_launch(void* const* d_in, const int* in_sizes, int n_in,
                              void* d_out, int out_size, void* d_ws, size_t ws_size,
                              hipStream_t stream) {
  const float* x  = (const float*)d_in[0];
  const float* fc = (const float*)d_in[1];
  const float* fs = (const float*)d_in[2];
  const float* Wq = (const float*)d_in[3];
  const float* Wk = (const float*)d_in[4];
  const float* Wv = (const float*)d_in[5];
  const float* Wo = (const float*)d_in[6];

  const size_t SZ = (size_t)4096 * 4096;
  ushort_t* xb  = (ushort_t*)d_ws;
  ushort_t* WqT = xb + SZ;
  ushort_t* WkT = WqT + SZ;
  ushort_t* WvT = WkT + SZ;
  ushort_t* WoT = WvT + SZ;
  ushort_t* qb  = WoT + SZ;
  ushort_t* kb  = qb + SZ;
  ushort_t* vT  = kb + SZ;
  ushort_t* yb  = vT + SZ;

  // prep: 4 weight transposes + x cast in one launch (z = 0..4)
  dim3 tg(64, 64, 5);
  k_prep<<<tg, 256, 0, stream>>>(Wq, Wk, Wv, Wo, x, WqT, xb);

  // merged Q,K,V^T projections (double-buffered, 2 blocks/CU — measured best)
  dim3 gq(512, 3);
  k_gemm_qkv<<<gq, 512, 0, stream>>>(xb, WqT, WkT, WvT, qb, kb, vT, fc, fs);

  k_attn<<<512, 512, 0, stream>>>(qb, kb, vT, yb);

  k_gemm_wo<<<512, 512, 0, stream>>>(yb, WoT, (float*)d_out);
}